// Round 19
// baseline (282.342 us; speedup 1.0000x reference)
//
#include <hip/hip_runtime.h>

#define B_DIM 4096
#define T_DIM 200
#define D_DIM 128
#define H_DIM 16
#define NCH   13    // chunks of 16 rows: 13*16 = 208; rows 200-207 masked off

typedef _Float16 h2 __attribute__((ext_vector_type(2)));
typedef _Float16 h8 __attribute__((ext_vector_type(8)));   // MFMA f16 operand
typedef __fp16   g2 __attribute__((ext_vector_type(2)));   // cvt_pkrtz return type
typedef float    f4 __attribute__((ext_vector_type(4)));   // MFMA accumulator
union F8 { h8 v; h2 p[4]; unsigned int u[4]; };
union HU { unsigned int u; h2 h; };
union U4F8 { uint4 q; h8 v; };

__device__ __forceinline__ h2 pkh(float a, float b) {
    g2 t = __builtin_amdgcn_cvt_pkrtz(a, b);   // v_cvt_pkrtz_f16_f32
    return __builtin_bit_cast(h2, t);
}
// VALU-pipe cross-lane move (v_mov_dpp). 0x12N = row_ror:N within each 16-lane row.
template<int CTRL>
__device__ __forceinline__ float dppmov(float x) {
    return __builtin_bit_cast(float,
        __builtin_amdgcn_update_dpp(0, __builtin_bit_cast(int, x), CTRL, 0xF, 0xF, true));
}
// full sum over the 16 lanes of a row via rotations (all VALU, no DS)
__device__ __forceinline__ float rorsum16(float x) {
    x += dppmov<0x121>(x);
    x += dppmov<0x122>(x);
    x += dppmov<0x124>(x);
    x += dppmov<0x128>(x);
    return x;
}

extern "C" __global__ __launch_bounds__(512)
void din_fused(const float* __restrict__ query,
               const float* __restrict__ facts,
               const int* __restrict__ mask,
               const float* __restrict__ W1,
               const float* __restrict__ b1,
               const float* __restrict__ W2,
               float* __restrict__ out)
{
    const int tid  = threadIdx.x;
    const int wid  = tid >> 6;        // wave = one b
    const int lane = tid & 63;
    const int rl   = lane & 15;       // A-row slot / B-col (=h) / D-col
    const int g    = lane >> 4;       // k-group; D rows 4g..4g+3
    const int b    = blockIdx.x * 8 + wid;

    __shared__ float W1bc[H_DIM * D_DIM];        // (W1b - W1c)[h][d]
    __shared__ float W1dd[H_DIM * D_DIM];        // W1d[h][d]
    __shared__ float W1ac[H_DIM * D_DIM];        // (W1a + W1c)[h][d]
    __shared__ unsigned int pool[8][1024];       // per-wave: wef staging, then fB fragments
    __shared__ float qwl[8][H_DIM];
    __shared__ float wxch[8][16];                // per-wave softmax-weight exchange

    const float* fb = facts + (size_t)b * (T_DIM * D_DIM);
    const int*   mb = mask  + (size_t)b * T_DIM;
    const float* qb = query + (size_t)b * D_DIM;

    // ---- half-chunk loads: half m = (chunk m>>1, s-pair m&1); 16 VGPRs each ----
    float4 H0[4], H1[4], H2[4];
    auto loadH = [&](int m, float4 (&H)[4]) {
        int c = m >> 1, sp = (m & 1) * 2;                  // s = sp, sp+1
        int r = 16 * c + rl; if (r > T_DIM - 1) r = T_DIM - 1;
        const float* p = fb + r * D_DIM + 8 * g + 32 * sp;
        H[0] = *(const float4*)(p);
        H[1] = *(const float4*)(p + 4);
        H[2] = *(const float4*)(p + 32);
        H[3] = *(const float4*)(p + 36);
    };
    loadH(0, H0); loadH(1, H1); loadH(2, H2);   // 12 dwordx4 fly across prologue

    // ---- mask -> ballot bits ----
    unsigned long long bal0, bal1, bal2, bal3;
    {
        int m0 = mb[lane];
        int m1 = mb[64 + lane];
        int m2 = mb[128 + lane];
        int m3 = (lane < 8) ? mb[192 + lane] : 0;          // rows >=200 masked off
        bal0 = __ballot(m0 != 0);
        bal1 = __ballot(m1 != 0);
        bal2 = __ballot(m2 != 0);
        bal3 = __ballot(m3 != 0);
    }

    // ---- one-time W1 transpose (only block-wide barrier) ----
    #pragma unroll
    for (int i = 0; i < 4; ++i) {
        int idx = tid * 4 + i;                             // h*128 + d
        int h = idx >> 7, d = idx & 127;
        W1bc[idx] = W1[(128 + d) * H_DIM + h] - W1[(256 + d) * H_DIM + h];
        W1dd[idx] = W1[(384 + d) * H_DIM + h];
        W1ac[idx] = W1[d * H_DIM + h] + W1[(256 + d) * H_DIM + h];
    }
    __syncthreads();

    // ---- per-wave qw ----
    {
        int h = lane & 15, dg = lane >> 4;
        float p = 0.f;
        #pragma unroll
        for (int k = 0; k < 8; ++k) {
            float4 a4 = *(const float4*)&W1ac[h * D_DIM + dg * 32 + 4 * k];
            float4 q4 = *(const float4*)(qb + dg * 32 + 4 * k);
            p += a4.x * q4.x + a4.y * q4.y + a4.z * q4.z + a4.w * q4.w;
        }
        p += __shfl_xor(p, 16);
        p += __shfl_xor(p, 32);
        if (lane < 16) qwl[wid][h] = p + b1[h];
    }
    // ---- weff -> per-wave LDS staging (h-major), f16x2 ----
    #pragma unroll
    for (int pass = 0; pass < 2; ++pass) {
        int h  = 8 * pass + (lane >> 3);
        int p0 = (lane & 7) * 8;                           // 8 d-pairs per lane
        unsigned int pk[8];
        #pragma unroll
        for (int u = 0; u < 8; ++u) {
            int d0 = 2 * (p0 + u);
            float a0 = W1bc[h * D_DIM + d0]     + qb[d0]     * W1dd[h * D_DIM + d0];
            float a1 = W1bc[h * D_DIM + d0 + 1] + qb[d0 + 1] * W1dd[h * D_DIM + d0 + 1];
            HU t; t.h = pkh(a0, a1); pk[u] = t.u;
        }
        *(uint4*)&pool[wid][h * 64 + p0]     = make_uint4(pk[0], pk[1], pk[2], pk[3]);
        *(uint4*)&pool[wid][h * 64 + p0 + 4] = make_uint4(pk[4], pk[5], pk[6], pk[7]);
    }
    asm volatile("s_waitcnt lgkmcnt(0)" ::: "memory");     // wave-private staging done

    // ---- one-time B-fragment gather (16-way conflict, once), then re-store
    //      fragment-major [s][lane] into the SAME (now dead) pool region ----
    {
        uint4 fBq[4];
        #pragma unroll
        for (int s = 0; s < 4; ++s)
            fBq[s] = *(const uint4*)&pool[wid][rl * 64 + 16 * s + 4 * g];
        asm volatile("s_waitcnt lgkmcnt(0)" ::: "memory"); // reads landed before rewrite
        #pragma unroll
        for (int s = 0; s < 4; ++s)
            *(uint4*)&pool[wid][s * 256 + lane * 4] = fBq[s];
        asm volatile("s_waitcnt lgkmcnt(0)" ::: "memory");
    }

    const float qv  = qwl[wid][rl];
    const float w2v = W2[rl];

    float a32[32];
    #pragma unroll
    for (int i = 0; i < 32; ++i) a32[i] = 0.f;
    float lw = 0.f;

    // ---- chunk body: cvt halves, reload them, MFMA with LDS-resident fB ----
    auto doChunk = [&](int c, float4 (&B0)[4], float4 (&B1)[4]) {
        F8 fa[4];
        fa[0].p[0] = pkh(B0[0].x, B0[0].y); fa[0].p[1] = pkh(B0[0].z, B0[0].w);
        fa[0].p[2] = pkh(B0[1].x, B0[1].y); fa[0].p[3] = pkh(B0[1].z, B0[1].w);
        fa[1].p[0] = pkh(B0[2].x, B0[2].y); fa[1].p[1] = pkh(B0[2].z, B0[2].w);
        fa[1].p[2] = pkh(B0[3].x, B0[3].y); fa[1].p[3] = pkh(B0[3].z, B0[3].w);
        if (2 * c + 3 < 2 * NCH) loadH(2 * c + 3, B0);     // reload freed buffer
        fa[2].p[0] = pkh(B1[0].x, B1[0].y); fa[2].p[1] = pkh(B1[0].z, B1[0].w);
        fa[2].p[2] = pkh(B1[1].x, B1[1].y); fa[2].p[3] = pkh(B1[1].z, B1[1].w);
        fa[3].p[0] = pkh(B1[2].x, B1[2].y); fa[3].p[1] = pkh(B1[2].z, B1[2].w);
        fa[3].p[2] = pkh(B1[3].x, B1[3].y); fa[3].p[3] = pkh(B1[3].z, B1[3].w);
        if (2 * c + 4 < 2 * NCH) loadH(2 * c + 4, B1);

        f4 D = {0.f, 0.f, 0.f, 0.f};                       // D[j]=pre[16c+4g+j][h=rl]
        #pragma unroll
        for (int s = 0; s < 4; ++s) {
            U4F8 w; w.q = *(const uint4*)&pool[wid][s * 256 + lane * 4];
            D = __builtin_amdgcn_mfma_f32_16x16x32_f16(fa[s].v, w.v, D, 0, 0, 0);
        }

        int r0 = 16 * c;
        unsigned long long wrd = r0 < 64 ? bal0 : r0 < 128 ? bal1 : r0 < 192 ? bal2 : bal3;
        unsigned long long sw  = wrd >> ((r0 & 63) + 4 * g);

        float wj[4];
        #pragma unroll
        for (int j = 0; j < 4; ++j) {
            float sc = w2v / (1.f + __expf(-(qv + D[j])));  // h-contribution
            sc = rorsum16(sc);                              // sum 16 h (VALU only)
            wj[j] = ((sw >> j) & 1) ? __expf(sc) : 0.f;     // deferred softmax
        }
        lw += wj[0] + wj[1] + wj[2] + wj[3];                // identical across group g

        if (rl == 0)                                        // rows -> row-slot lanes
            *(float4*)&wxch[wid][4 * g] = make_float4(wj[0], wj[1], wj[2], wj[3]);
        asm volatile("s_waitcnt lgkmcnt(0)" ::: "memory");
        float wv = wxch[wid][rl];                           // weight of lane's A-row

        #pragma unroll
        for (int s = 0; s < 4; ++s)
            #pragma unroll
            for (int e = 0; e < 4; ++e) {
                a32[8*s + 2*e]     += wv * (float)fa[s].p[e].x;
                a32[8*s + 2*e + 1] += wv * (float)fa[s].p[e].y;
            }
    };

    // ---- main loop: 3-half-buffer rotation, period 3 chunks ----
    #pragma unroll 1
    for (int cc = 0; cc + 2 < NCH; cc += 3) {              // cc = 0,3,6,9 -> chunks 0..11
        doChunk(cc,     H0, H1);
        doChunk(cc + 1, H2, H0);
        doChunk(cc + 2, H1, H2);
    }
    doChunk(12, H0, H1);                                   // tail chunk

    // ---- epilogue: l over 4 groups; acc over 16 row-slots (rotation-sum); store ----
    float l = lw;
    l += __shfl_xor(l, 16);
    l += __shfl_xor(l, 32);
    float inv = 1.f / l;
    #pragma unroll
    for (int i = 0; i < 32; ++i) a32[i] = rorsum16(a32[i]);
    if (rl == 0) {                                         // group g: d = 32s + 8g + 0..7
        float* ob = out + (size_t)b * D_DIM + 8 * g;
        #pragma unroll
        for (int s = 0; s < 4; ++s) {
            *(float4*)(ob + 32 * s) =
                make_float4(a32[8*s]*inv, a32[8*s+1]*inv, a32[8*s+2]*inv, a32[8*s+3]*inv);
            *(float4*)(ob + 32 * s + 4) =
                make_float4(a32[8*s+4]*inv, a32[8*s+5]*inv, a32[8*s+6]*inv, a32[8*s+7]*inv);
        }
    }
}

extern "C" void kernel_launch(void* const* d_in, const int* in_sizes, int n_in,
                              void* d_out, int out_size, void* d_ws, size_t ws_size,
                              hipStream_t stream) {
    const float* query = (const float*)d_in[0];
    const float* facts = (const float*)d_in[1];
    const int*   mask  = (const int*)d_in[2];   // harness delivers bool as int32
    const float* W1    = (const float*)d_in[3];
    const float* b1    = (const float*)d_in[4];
    const float* W2    = (const float*)d_in[5];
    // d_in[6] = b2: dropped (cancels in softmax ratio)
    float* out = (float*)d_out;
    (void)in_sizes; (void)n_in; (void)out_size; (void)d_ws; (void)ws_size;

    din_fused<<<dim3(B_DIM / 8), dim3(512), 0, stream>>>(
        query, facts, mask, W1, b1, W2, out);
}

// Round 20
// 93.490 us; speedup vs baseline: 3.0200x; 3.0200x over previous
//
#include <hip/hip_runtime.h>

#define B_DIM 4096
#define T_DIM 200
#define D_DIM 128
#define H_DIM 16
#define NCH   13    // chunks of 16 rows: 13*16 = 208; rows 200-207 masked off

typedef _Float16 h2 __attribute__((ext_vector_type(2)));
typedef _Float16 h8 __attribute__((ext_vector_type(8)));   // MFMA f16 operand
typedef __fp16   g2 __attribute__((ext_vector_type(2)));   // cvt_pkrtz return type
typedef float    f4 __attribute__((ext_vector_type(4)));   // MFMA accumulator
union F8 { h8 v; h2 p[4]; unsigned int u[4]; };
union HU { unsigned int u; h2 h; };

__device__ __forceinline__ h2 pkh(float a, float b) {
    g2 t = __builtin_amdgcn_cvt_pkrtz(a, b);   // v_cvt_pkrtz_f16_f32
    return __builtin_bit_cast(h2, t);
}
// VALU-pipe cross-lane move (v_mov_dpp). 0x12N = row_ror:N within each 16-lane row.
template<int CTRL>
__device__ __forceinline__ float dppmov(float x) {
    return __builtin_bit_cast(float,
        __builtin_amdgcn_update_dpp(0, __builtin_bit_cast(int, x), CTRL, 0xF, 0xF, true));
}
// full sum over the 16 lanes of a row via rotations (all VALU, no DS)
__device__ __forceinline__ float rorsum16(float x) {
    x += dppmov<0x121>(x);
    x += dppmov<0x122>(x);
    x += dppmov<0x124>(x);
    x += dppmov<0x128>(x);
    return x;
}

extern "C" __global__ __launch_bounds__(512)
void din_fused(const float* __restrict__ query,
               const float* __restrict__ facts,
               const int* __restrict__ mask,
               const float* __restrict__ W1,
               const float* __restrict__ b1,
               const float* __restrict__ W2,
               float* __restrict__ out)
{
    const int tid  = threadIdx.x;
    const int wid  = tid >> 6;        // wave = one b
    const int lane = tid & 63;
    const int rl   = lane & 15;       // A-row slot / B-col (=h) / D-col
    const int g    = lane >> 4;       // k-group; D rows 4g..4g+3
    const int b    = blockIdx.x * 8 + wid;

    __shared__ float W1bc[H_DIM * D_DIM];        // (W1b - W1c)[h][d]
    __shared__ float W1dd[H_DIM * D_DIM];        // W1d[h][d]
    __shared__ float W1ac[H_DIM * D_DIM];        // (W1a + W1c)[h][d]
    __shared__ unsigned int wef[8][H_DIM * 64];  // per-wave f16x2 weff staging
    __shared__ float qwl[8][H_DIM];
    __shared__ float wxch[8][16];                // per-wave softmax-weight exchange

    const float* fb = facts + (size_t)b * (T_DIM * D_DIM);
    const int*   mb = mask  + (size_t)b * T_DIM;
    const float* qb = query + (size_t)b * D_DIM;

    // ---- facts chunk-0 loads FIRST (fly across whole prologue) ----
    // Lane holds A-fragment data: row rl, d = 32s + 8g + e (e=0..7)
    float4 F[8];
    auto loadF = [&](int c) {
        int r = 16 * c + rl; if (r > T_DIM - 1) r = T_DIM - 1;   // tail clamp
        const float* p = fb + r * D_DIM + 8 * g;
        #pragma unroll
        for (int s = 0; s < 4; ++s) {
            F[2*s]     = *(const float4*)(p + 32 * s);
            F[2*s + 1] = *(const float4*)(p + 32 * s + 4);
        }
    };
    loadF(0);

    // ---- mask -> ballot bits (one read per wave; guards = register bits) ----
    unsigned long long bal0, bal1, bal2, bal3;
    {
        int m0 = mb[lane];
        int m1 = mb[64 + lane];
        int m2 = mb[128 + lane];
        int m3 = (lane < 8) ? mb[192 + lane] : 0;   // rows >=200 masked off
        bal0 = __ballot(m0 != 0);
        bal1 = __ballot(m1 != 0);
        bal2 = __ballot(m2 != 0);
        bal3 = __ballot(m3 != 0);
    }

    // ---- one-time W1 transpose (only block-wide barrier) ----
    #pragma unroll
    for (int i = 0; i < 4; ++i) {
        int idx = tid * 4 + i;                   // h*128 + d
        int h = idx >> 7, d = idx & 127;
        W1bc[idx] = W1[(128 + d) * H_DIM + h] - W1[(256 + d) * H_DIM + h];
        W1dd[idx] = W1[(384 + d) * H_DIM + h];
        W1ac[idx] = W1[d * H_DIM + h] + W1[(256 + d) * H_DIM + h];
    }
    __syncthreads();

    // ---- per-wave qw ----
    {
        int h = lane & 15, dg = lane >> 4;
        float p = 0.f;
        #pragma unroll
        for (int k = 0; k < 8; ++k) {
            float4 a4 = *(const float4*)&W1ac[h * D_DIM + dg * 32 + 4 * k];
            float4 q4 = *(const float4*)(qb + dg * 32 + 4 * k);
            p += a4.x * q4.x + a4.y * q4.y + a4.z * q4.z + a4.w * q4.w;
        }
        p += __shfl_xor(p, 16);
        p += __shfl_xor(p, 32);
        if (lane < 16) qwl[wid][h] = p + b1[h];
    }
    // ---- weff -> per-wave LDS staging (conflict-free build), f16x2 ----
    #pragma unroll
    for (int pass = 0; pass < 2; ++pass) {
        int h  = 8 * pass + (lane >> 3);
        int p0 = (lane & 7) * 8;                 // 8 d-pairs per lane
        unsigned int pk[8];
        #pragma unroll
        for (int u = 0; u < 8; ++u) {
            int d0 = 2 * (p0 + u);
            float a0 = W1bc[h * D_DIM + d0]     + qb[d0]     * W1dd[h * D_DIM + d0];
            float a1 = W1bc[h * D_DIM + d0 + 1] + qb[d0 + 1] * W1dd[h * D_DIM + d0 + 1];
            HU t; t.h = pkh(a0, a1); pk[u] = t.u;
        }
        *(uint4*)&wef[wid][h * 64 + p0]     = make_uint4(pk[0], pk[1], pk[2], pk[3]);
        *(uint4*)&wef[wid][h * 64 + p0 + 4] = make_uint4(pk[4], pk[5], pk[6], pk[7]);
    }
    asm volatile("s_waitcnt lgkmcnt(0)" ::: "memory");   // wave-private LDS RAW

    // ---- gather B-fragments: lane = col h=rl, k = 32s + 8g + e (one-time) ----
    F8 fB[4];
    #pragma unroll
    for (int s = 0; s < 4; ++s) {
        uint4 t = *(const uint4*)&wef[wid][rl * 64 + 16 * s + 4 * g];
        fB[s].u[0] = t.x; fB[s].u[1] = t.y; fB[s].u[2] = t.z; fB[s].u[3] = t.w;
    }
    const float qv  = qwl[wid][rl];
    const float w2v = W2[rl];

    float a32[32];
    #pragma unroll
    for (int i = 0; i < 32; ++i) a32[i] = 0.f;
    float lw = 0.f;

    // ---- main loop: convert-then-reload pipelining, MFMA scoring ----
    #pragma unroll 1
    for (int c = 0; c < NCH; ++c) {
        F8 fa[4];                                // A-fragments (F dies here)
        #pragma unroll
        for (int s = 0; s < 4; ++s) {
            fa[s].p[0] = pkh(F[2*s].x,     F[2*s].y);
            fa[s].p[1] = pkh(F[2*s].z,     F[2*s].w);
            fa[s].p[2] = pkh(F[2*s + 1].x, F[2*s + 1].y);
            fa[s].p[3] = pkh(F[2*s + 1].z, F[2*s + 1].w);
        }
        if (c + 1 < NCH) loadF(c + 1);           // next chunk lands under compute

        f4 D = {0.f, 0.f, 0.f, 0.f};             // D[j] = pre[16c + 4g + j][h=rl]
        D = __builtin_amdgcn_mfma_f32_16x16x32_f16(fa[0].v, fB[0].v, D, 0, 0, 0);
        D = __builtin_amdgcn_mfma_f32_16x16x32_f16(fa[1].v, fB[1].v, D, 0, 0, 0);
        D = __builtin_amdgcn_mfma_f32_16x16x32_f16(fa[2].v, fB[2].v, D, 0, 0, 0);
        D = __builtin_amdgcn_mfma_f32_16x16x32_f16(fa[3].v, fB[3].v, D, 0, 0, 0);

        int r0 = 16 * c;
        unsigned long long wrd = r0 < 64 ? bal0 : r0 < 128 ? bal1 : r0 < 192 ? bal2 : bal3;
        unsigned long long sw  = wrd >> ((r0 & 63) + 4 * g);

        float wj[4];
        #pragma unroll
        for (int j = 0; j < 4; ++j) {
            float sc = w2v / (1.f + __expf(-(qv + D[j])));   // h-contribution
            sc = rorsum16(sc);                                // sum 16 h (VALU only)
            wj[j] = ((sw >> j) & 1) ? __expf(sc) : 0.f;       // deferred softmax
        }
        lw += wj[0] + wj[1] + wj[2] + wj[3];      // identical across group g

        if (rl == 0)                              // w-exchange: rows -> row-slot lanes
            *(float4*)&wxch[wid][4 * g] = make_float4(wj[0], wj[1], wj[2], wj[3]);
        asm volatile("s_waitcnt lgkmcnt(0)" ::: "memory");
        float wv = wxch[wid][rl];                 // weight of this lane's A-row

        #pragma unroll
        for (int s = 0; s < 4; ++s)
            #pragma unroll
            for (int e = 0; e < 4; ++e) {
                a32[8*s + 2*e]     += wv * (float)fa[s].p[e].x;
                a32[8*s + 2*e + 1] += wv * (float)fa[s].p[e].y;
            }
    }

    // ---- epilogue: l over 4 groups; acc over 16 row-slots (rotation-sum); store ----
    float l = lw;
    l += __shfl_xor(l, 16);
    l += __shfl_xor(l, 32);
    float inv = 1.f / l;
    #pragma unroll
    for (int i = 0; i < 32; ++i) a32[i] = rorsum16(a32[i]);
    if (rl == 0) {                                // group g writes d = 32s + 8g + 0..7
        float* ob = out + (size_t)b * D_DIM + 8 * g;
        #pragma unroll
        for (int s = 0; s < 4; ++s) {
            *(float4*)(ob + 32 * s) =
                make_float4(a32[8*s]*inv, a32[8*s+1]*inv, a32[8*s+2]*inv, a32[8*s+3]*inv);
            *(float4*)(ob + 32 * s + 4) =
                make_float4(a32[8*s+4]*inv, a32[8*s+5]*inv, a32[8*s+6]*inv, a32[8*s+7]*inv);
        }
    }
}

extern "C" void kernel_launch(void* const* d_in, const int* in_sizes, int n_in,
                              void* d_out, int out_size, void* d_ws, size_t ws_size,
                              hipStream_t stream) {
    const float* query = (const float*)d_in[0];
    const float* facts = (const float*)d_in[1];
    const int*   mask  = (const int*)d_in[2];   // harness delivers bool as int32
    const float* W1    = (const float*)d_in[3];
    const float* b1    = (const float*)d_in[4];
    const float* W2    = (const float*)d_in[5];
    // d_in[6] = b2: dropped (cancels in softmax ratio)
    float* out = (float*)d_out;
    (void)in_sizes; (void)n_in; (void)out_size; (void)d_ws; (void)ws_size;

    din_fused<<<dim3(B_DIM / 8), dim3(512), 0, stream>>>(
        query, facts, mask, W1, b1, W2, out);
}